// Round 7
// baseline (217.706 us; speedup 1.0000x reference)
//
#include <hip/hip_runtime.h>
#include <hip/hip_cooperative_groups.h>

namespace cg = cooperative_groups;

#define B_DIM 64
#define S_LEN 2048
#define H_DIM 256
#define TWO_PI 6.283185307179586f

// Fused cooperative config: 1024 blocks x 512 threads = 4 blocks/CU, 32 waves/CU.
#define NBLK 1024
#define NTHR 512
#define NWAVE 8            // waves per block
#define ROWS_PER_BLK 128   // each block owns 1/16 of one b's rows

typedef float f32x4 __attribute__((ext_vector_type(4)));

// ---------------- fused cooperative kernel ----------------
// Phase 1: per-block partials (S0,C1,S1) over its 128 rows -> ws[blk][768]
// grid.sync
// Phase 2: per-block combine of the 16 partials of its b (into LDS)
// Phase 3: low-pass reconstruct + residual + LayerNorm over the SAME rows
// (x re-read is L3-resident; out stores non-temporal so they don't evict x).
__global__ __launch_bounds__(NTHR, 8) void k_fused(const float* __restrict__ x,
                                                   const float* __restrict__ sqrt_beta,
                                                   const float* __restrict__ lnw,
                                                   const float* __restrict__ lnb,
                                                   float* __restrict__ out,
                                                   float* __restrict__ ws) {
    const int blk = blockIdx.x;
    const int b = blk >> 4;
    const int q = blk & 15;
    const int tid = threadIdx.x;
    const int lane = tid & 63;
    const int wave = tid >> 6;   // 0..7
    const int h0 = lane * 4;

    const float wfreq = TWO_PI / (float)S_LEN;
    const int t_base = q * ROWS_PER_BLK;
    const float* __restrict__ px = x + ((size_t)b * S_LEN + t_base) * H_DIM + h0;

    __shared__ float red[NWAVE][3 * H_DIM];   // 24 KB

    // ---- Phase 1: wave w covers rows r === w (mod 8); 4 loads in flight ----
    f32x4 s0v = {0.f, 0.f, 0.f, 0.f};
    f32x4 c1v = {0.f, 0.f, 0.f, 0.f};
    f32x4 s1v = {0.f, 0.f, 0.f, 0.f};
#pragma unroll
    for (int kk = 0; kk < ROWS_PER_BLK / 32; ++kk) {
        const int r0 = wave + kk * 32;
        const f32x4 v0 = *reinterpret_cast<const f32x4*>(px + (size_t)(r0     ) * H_DIM);
        const f32x4 v1 = *reinterpret_cast<const f32x4*>(px + (size_t)(r0 +  8) * H_DIM);
        const f32x4 v2 = *reinterpret_cast<const f32x4*>(px + (size_t)(r0 + 16) * H_DIM);
        const f32x4 v3 = *reinterpret_cast<const f32x4*>(px + (size_t)(r0 + 24) * H_DIM);
        float sn0, cs0, sn1, cs1, sn2, cs2, sn3, cs3;
        __sincosf(wfreq * (float)(t_base + r0     ), &sn0, &cs0);
        __sincosf(wfreq * (float)(t_base + r0 +  8), &sn1, &cs1);
        __sincosf(wfreq * (float)(t_base + r0 + 16), &sn2, &cs2);
        __sincosf(wfreq * (float)(t_base + r0 + 24), &sn3, &cs3);
        s0v += (v0 + v1) + (v2 + v3);
        c1v += (v0 * cs0 + v1 * cs1) + (v2 * cs2 + v3 * cs3);
        s1v += (v0 * sn0 + v1 * sn1) + (v2 * sn2 + v3 * sn3);
    }

#pragma unroll
    for (int j = 0; j < 4; ++j) {
        red[wave][0 * H_DIM + h0 + j] = s0v[j];
        red[wave][1 * H_DIM + h0 + j] = c1v[j];
        red[wave][2 * H_DIM + h0 + j] = s1v[j];
    }
    __syncthreads();
    for (int j = tid; j < 3 * H_DIM; j += NTHR) {
        float acc = 0.f;
#pragma unroll
        for (int w = 0; w < NWAVE; ++w) acc += red[w][j];
        ws[(size_t)blk * (3 * H_DIM) + j] = acc;
    }

    cg::this_grid().sync();

    // ---- Phase 2: combine the 16 partials of this b into LDS (red[0]) ----
    const int pbase = blk & ~15;
    for (int j = tid; j < 3 * H_DIM; j += NTHR) {
        float acc = 0.f;
#pragma unroll
        for (int k = 0; k < 16; ++k)
            acc += ws[(size_t)(pbase + k) * (3 * H_DIM) + j];
        red[0][j] = acc;
    }
    __syncthreads();

    const f32x4 S0 = *reinterpret_cast<const f32x4*>(&red[0][h0]);
    const f32x4 C1 = *reinterpret_cast<const f32x4*>(&red[0][H_DIM + h0]);
    const f32x4 S1 = *reinterpret_cast<const f32x4*>(&red[0][2 * H_DIM + h0]);
    const f32x4 sb = *reinterpret_cast<const f32x4*>(sqrt_beta + h0);
    const f32x4 Wv = *reinterpret_cast<const f32x4*>(lnw + h0);
    const f32x4 Bv = *reinterpret_cast<const f32x4*>(lnb + h0);
    const f32x4 b2 = sb * sb;
    const f32x4 CA = b2 + 1.f;   // coefficient on x
    const f32x4 CB = 1.f - b2;   // coefficient on low_pass
    const float invS = 1.f / (float)S_LEN;

    // ---- Phase 3: 2 rows/iteration, interleaved reductions ----
    float* __restrict__ po = out + ((size_t)b * S_LEN + t_base) * H_DIM + h0;
#pragma unroll
    for (int k = 0; k < ROWS_PER_BLK / NWAVE; k += 2) {
        const int r0 = wave + k * NWAVE;
        const int r1 = wave + (k + 1) * NWAVE;
        const f32x4 va = *reinterpret_cast<const f32x4*>(px + (size_t)r0 * H_DIM);
        const f32x4 vb = *reinterpret_cast<const f32x4*>(px + (size_t)r1 * H_DIM);
        float sna, csa, snb, csb;
        __sincosf(wfreq * (float)(t_base + r0), &sna, &csa);
        __sincosf(wfreq * (float)(t_base + r1), &snb, &csb);
        const f32x4 ya = CB * ((S0 + (C1 * csa + S1 * sna) * 2.f) * invS) + CA * va;
        const f32x4 yb = CB * ((S0 + (C1 * csb + S1 * snb) * 2.f) * invS) + CA * vb;

        float suma = ya.x + ya.y + ya.z + ya.w;
        float sqa  = ya.x * ya.x + ya.y * ya.y + ya.z * ya.z + ya.w * ya.w;
        float sumb = yb.x + yb.y + yb.z + yb.w;
        float sqb  = yb.x * yb.x + yb.y * yb.y + yb.z * yb.z + yb.w * yb.w;
#pragma unroll
        for (int m = 1; m < 64; m <<= 1) {
            suma += __shfl_xor(suma, m, 64);
            sqa  += __shfl_xor(sqa,  m, 64);
            sumb += __shfl_xor(sumb, m, 64);
            sqb  += __shfl_xor(sqb,  m, 64);
        }
        const float meana = suma * (1.f / (float)H_DIM);
        const float vara = sqa * (1.f / (float)H_DIM) - meana * meana;
        const float rstda = rsqrtf(vara + 1e-5f);
        const float meanb = sumb * (1.f / (float)H_DIM);
        const float varb = sqb * (1.f / (float)H_DIM) - meanb * meanb;
        const float rstdb = rsqrtf(varb + 1e-5f);

        f32x4 oa = (ya - meana) * rstda * Wv + Bv;
        f32x4 ob = (yb - meanb) * rstdb * Wv + Bv;
        __builtin_nontemporal_store(oa, reinterpret_cast<f32x4*>(po + (size_t)r0 * H_DIM));
        __builtin_nontemporal_store(ob, reinterpret_cast<f32x4*>(po + (size_t)r1 * H_DIM));
    }
}

// ---------------- fallback (R2-style 3-kernel, known 72.7 us) ----------------
__global__ __launch_bounds__(256) void k_partial(const float* __restrict__ x,
                                                 float* __restrict__ partials,
                                                 int rows_per_split) {
    const int b = blockIdx.x;
    const int split = blockIdx.y;
    const int tid = threadIdx.x;
    const int lane = tid & 63;
    const int wave = tid >> 6;
    const int h0 = lane * 4;

    f32x4 s0v = {0.f, 0.f, 0.f, 0.f};
    f32x4 c1v = {0.f, 0.f, 0.f, 0.f};
    f32x4 s1v = {0.f, 0.f, 0.f, 0.f};

    const int t_begin = split * rows_per_split;
    const int t_end = t_begin + rows_per_split;
    const float wfreq = TWO_PI / (float)S_LEN;

    for (int t = t_begin + wave; t < t_end; t += 4) {
        const f32x4 v = *reinterpret_cast<const f32x4*>(
            x + ((size_t)b * S_LEN + t) * H_DIM + h0);
        float sn, cs;
        __sincosf(wfreq * (float)t, &sn, &cs);
        s0v += v;
        c1v += v * cs;
        s1v += v * sn;
    }

    __shared__ float red[4][3 * H_DIM];
#pragma unroll
    for (int j = 0; j < 4; ++j) {
        red[wave][0 * H_DIM + h0 + j] = s0v[j];
        red[wave][1 * H_DIM + h0 + j] = c1v[j];
        red[wave][2 * H_DIM + h0 + j] = s1v[j];
    }
    __syncthreads();
#pragma unroll
    for (int k = 0; k < 3; ++k) {
        const int v = tid + k * 256;
        partials[((size_t)(split * B_DIM + b)) * (3 * H_DIM) + v] =
            red[0][v] + red[1][v] + red[2][v] + red[3][v];
    }
}

__global__ __launch_bounds__(256) void k_reduce(const float* __restrict__ partials,
                                                float* __restrict__ sums,
                                                int nsplit) {
    const int j = blockIdx.x * 256 + threadIdx.x;
    float acc = 0.f;
    for (int s = 0; s < nsplit; ++s)
        acc += partials[(size_t)s * (B_DIM * 3 * H_DIM) + j];
    sums[j] = acc;
}

#define FB_ROWS 16
__global__ __launch_bounds__(256) void k_final(const float* __restrict__ x,
                                               const float* __restrict__ sums,
                                               const float* __restrict__ sqrt_beta,
                                               const float* __restrict__ lnw,
                                               const float* __restrict__ lnb,
                                               float* __restrict__ out) {
    const int blocks_per_b = S_LEN / FB_ROWS;
    const int b = blockIdx.x / blocks_per_b;
    const int tchunk = blockIdx.x % blocks_per_b;
    const int tid = threadIdx.x;
    const int lane = tid & 63;
    const int wave = tid >> 6;

    __shared__ float sS0[H_DIM], sC1[H_DIM], sS1[H_DIM];
    __shared__ float sCA[H_DIM], sCB[H_DIM], sW[H_DIM], sBi[H_DIM];
    {
        const int h = tid;
        sS0[h] = sums[b * 768 + h];
        sC1[h] = sums[b * 768 + 256 + h];
        sS1[h] = sums[b * 768 + 512 + h];
        const float s = sqrt_beta[h];
        const float b2 = s * s;
        sCA[h] = 1.f + b2;
        sCB[h] = 1.f - b2;
        sW[h] = lnw[h];
        sBi[h] = lnb[h];
    }
    __syncthreads();

    const float invS = 1.f / (float)S_LEN;
    const float wfreq = TWO_PI / (float)S_LEN;
    const int h0 = lane * 4;

#pragma unroll
    for (int r = 0; r < FB_ROWS / 4; ++r) {
        const int t = tchunk * FB_ROWS + wave * (FB_ROWS / 4) + r;
        float sn, cs;
        __sincosf(wfreq * (float)t, &sn, &cs);

        const size_t base = ((size_t)b * S_LEN + t) * H_DIM + h0;
        const f32x4 v = *reinterpret_cast<const f32x4*>(x + base);

        float y[4];
        float sum = 0.f, sumsq = 0.f;
#pragma unroll
        for (int j = 0; j < 4; ++j) {
            const int h = h0 + j;
            const float lp = invS * (sS0[h] + 2.f * (sC1[h] * cs + sS1[h] * sn));
            const float yy = sCB[h] * lp + sCA[h] * v[j];
            y[j] = yy;
            sum += yy;
            sumsq += yy * yy;
        }
#pragma unroll
        for (int m = 1; m < 64; m <<= 1) {
            sum += __shfl_xor(sum, m, 64);
            sumsq += __shfl_xor(sumsq, m, 64);
        }
        const float mean = sum * (1.f / (float)H_DIM);
        const float var = sumsq * (1.f / (float)H_DIM) - mean * mean;
        const float rstd = rsqrtf(var + 1e-5f);

        f32x4 o;
        o.x = (y[0] - mean) * rstd * sW[h0 + 0] + sBi[h0 + 0];
        o.y = (y[1] - mean) * rstd * sW[h0 + 1] + sBi[h0 + 1];
        o.z = (y[2] - mean) * rstd * sW[h0 + 2] + sBi[h0 + 2];
        o.w = (y[3] - mean) * rstd * sW[h0 + 3] + sBi[h0 + 3];
        *reinterpret_cast<f32x4*>(out + base) = o;
    }
}

extern "C" void kernel_launch(void* const* d_in, const int* in_sizes, int n_in,
                              void* d_out, int out_size, void* d_ws, size_t ws_size,
                              hipStream_t stream) {
    const float* x  = (const float*)d_in[0];
    const float* sb = (const float*)d_in[1];
    const float* w  = (const float*)d_in[2];
    const float* bi = (const float*)d_in[3];
    float* out = (float*)d_out;
    float* ws = (float*)d_ws;   // fused needs 1024*768*4 = 3 MB

    void* args[] = {(void*)&x, (void*)&sb, (void*)&w, (void*)&bi,
                    (void*)&out, (void*)&ws};
    hipError_t err = hipLaunchCooperativeKernel((const void*)k_fused, dim3(NBLK),
                                                dim3(NTHR), args, 0, stream);
    if (err != hipSuccess) {
        // deterministic fallback: R2-style 3-kernel path
        int nsplit = 16;
        while (nsplit > 1 &&
               ((size_t)(nsplit + 1) * B_DIM * 3 * H_DIM * sizeof(float)) > ws_size)
            nsplit >>= 1;
        float* partials = (float*)d_ws;
        float* sums = partials + (size_t)nsplit * B_DIM * 3 * H_DIM;
        k_partial<<<dim3(B_DIM, nsplit), 256, 0, stream>>>(x, partials, S_LEN / nsplit);
        k_reduce<<<(B_DIM * 3 * H_DIM) / 256, 256, 0, stream>>>(partials, sums, nsplit);
        k_final<<<B_DIM * (S_LEN / FB_ROWS), 256, 0, stream>>>(x, sums, sb, w, bi, out);
    }
}

// Round 8
// 75.727 us; speedup vs baseline: 2.8749x; 2.8749x over previous
//
#include <hip/hip_runtime.h>

#define B_DIM 64
#define S_LEN 2048
#define H_DIM 256
#define TWO_PI 6.283185307179586f

typedef float f32x4 __attribute__((ext_vector_type(4)));

// Pass 1: per (b, split) partial reductions of S0 = sum_t x, C1 = sum_t x*cos,
// S1 = sum_t x*sin. Block: 256 threads = 4 waves; wave w covers rows
// t === w (mod 4) in the split, unrolled x4 -> 4 independent float4 loads in
// flight per wave (16B/lane, 1KB/wave each).
__global__ __launch_bounds__(256) void k_partial(const float* __restrict__ x,
                                                 float* __restrict__ partials,
                                                 int rows_per_split) {
    const int b = blockIdx.x;
    const int split = blockIdx.y;
    const int tid = threadIdx.x;
    const int lane = tid & 63;
    const int wave = tid >> 6;
    const int h0 = lane * 4;

    f32x4 s0v = {0.f, 0.f, 0.f, 0.f};
    f32x4 c1v = {0.f, 0.f, 0.f, 0.f};
    f32x4 s1v = {0.f, 0.f, 0.f, 0.f};

    const int t_begin = split * rows_per_split;
    const int t_end = t_begin + rows_per_split;   // rows_per_split % 16 == 0
    const float wfreq = TWO_PI / (float)S_LEN;
    const float* __restrict__ pxb = x + (size_t)b * S_LEN * H_DIM + h0;

    for (int t = t_begin + wave; t < t_end; t += 16) {
        const f32x4 v0 = *reinterpret_cast<const f32x4*>(pxb + (size_t)(t     ) * H_DIM);
        const f32x4 v1 = *reinterpret_cast<const f32x4*>(pxb + (size_t)(t +  4) * H_DIM);
        const f32x4 v2 = *reinterpret_cast<const f32x4*>(pxb + (size_t)(t +  8) * H_DIM);
        const f32x4 v3 = *reinterpret_cast<const f32x4*>(pxb + (size_t)(t + 12) * H_DIM);
        float sn0, cs0, sn1, cs1, sn2, cs2, sn3, cs3;
        __sincosf(wfreq * (float)(t     ), &sn0, &cs0);
        __sincosf(wfreq * (float)(t +  4), &sn1, &cs1);
        __sincosf(wfreq * (float)(t +  8), &sn2, &cs2);
        __sincosf(wfreq * (float)(t + 12), &sn3, &cs3);
        s0v += (v0 + v1) + (v2 + v3);
        c1v += (v0 * cs0 + v1 * cs1) + (v2 * cs2 + v3 * cs3);
        s1v += (v0 * sn0 + v1 * sn1) + (v2 * sn2 + v3 * sn3);
    }

    __shared__ float red[4][3 * H_DIM];
#pragma unroll
    for (int j = 0; j < 4; ++j) {
        red[wave][0 * H_DIM + h0 + j] = s0v[j];
        red[wave][1 * H_DIM + h0 + j] = c1v[j];
        red[wave][2 * H_DIM + h0 + j] = s1v[j];
    }
    __syncthreads();

    // 768 values (3 comps x 256 h); each of 256 threads reduces 3 across 4 waves.
#pragma unroll
    for (int k = 0; k < 3; ++k) {
        const int v = tid + k * 256;
        partials[((size_t)(split * B_DIM + b)) * (3 * H_DIM) + v] =
            red[0][v] + red[1][v] + red[2][v] + red[3][v];
    }
}

// Pass 2 (fused into pass 3): each block combines the nsplit partials of its b
// while staging into LDS, then does low-pass reconstruct + residual + LayerNorm.
// Block: 256 threads = 4 waves; block covers 16 rows (4 rows per wave).
// partials (3 MB) are L2-resident -> the 48 combine loads/thread are cheap and
// hidden by the 32 blocks/CU of concurrency.
#define FB_ROWS 16
__global__ __launch_bounds__(256) void k_final(const float* __restrict__ x,
                                               const float* __restrict__ partials,
                                               const float* __restrict__ sqrt_beta,
                                               const float* __restrict__ lnw,
                                               const float* __restrict__ lnb,
                                               float* __restrict__ out,
                                               int nsplit) {
    const int blocks_per_b = S_LEN / FB_ROWS;
    const int b = blockIdx.x / blocks_per_b;
    const int tchunk = blockIdx.x % blocks_per_b;
    const int tid = threadIdx.x;
    const int lane = tid & 63;
    const int wave = tid >> 6;

    __shared__ float sS0[H_DIM], sC1[H_DIM], sS1[H_DIM];
    __shared__ float sCA[H_DIM], sCB[H_DIM], sW[H_DIM], sBi[H_DIM];
    {
        const int h = tid;
        float a0 = 0.f, a1 = 0.f, a2 = 0.f;
        for (int p = 0; p < nsplit; ++p) {
            const float* pp = partials + ((size_t)(p * B_DIM + b)) * (3 * H_DIM);
            a0 += pp[h];
            a1 += pp[256 + h];
            a2 += pp[512 + h];
        }
        sS0[h] = a0;
        sC1[h] = a1;
        sS1[h] = a2;
        const float s = sqrt_beta[h];
        const float b2 = s * s;
        sCA[h] = 1.f + b2;   // coefficient on x
        sCB[h] = 1.f - b2;   // coefficient on low_pass
        sW[h] = lnw[h];
        sBi[h] = lnb[h];
    }
    __syncthreads();

    const float invS = 1.f / (float)S_LEN;
    const float wfreq = TWO_PI / (float)S_LEN;
    const int h0 = lane * 4;

#pragma unroll
    for (int r = 0; r < FB_ROWS / 4; ++r) {
        const int t = tchunk * FB_ROWS + wave * (FB_ROWS / 4) + r;
        float sn, cs;
        __sincosf(wfreq * (float)t, &sn, &cs);

        const size_t base = ((size_t)b * S_LEN + t) * H_DIM + h0;
        const f32x4 v = *reinterpret_cast<const f32x4*>(x + base);

        float y[4];
        float sum = 0.f, sumsq = 0.f;
#pragma unroll
        for (int j = 0; j < 4; ++j) {
            const int h = h0 + j;
            const float lp = invS * (sS0[h] + 2.f * (sC1[h] * cs + sS1[h] * sn));
            const float yy = sCB[h] * lp + sCA[h] * v[j];
            y[j] = yy;
            sum += yy;
            sumsq += yy * yy;
        }
#pragma unroll
        for (int m = 1; m < 64; m <<= 1) {
            sum += __shfl_xor(sum, m, 64);
            sumsq += __shfl_xor(sumsq, m, 64);
        }
        const float mean = sum * (1.f / (float)H_DIM);
        const float var = sumsq * (1.f / (float)H_DIM) - mean * mean;
        const float rstd = rsqrtf(var + 1e-5f);

        f32x4 o;
        o.x = (y[0] - mean) * rstd * sW[h0 + 0] + sBi[h0 + 0];
        o.y = (y[1] - mean) * rstd * sW[h0 + 1] + sBi[h0 + 1];
        o.z = (y[2] - mean) * rstd * sW[h0 + 2] + sBi[h0 + 2];
        o.w = (y[3] - mean) * rstd * sW[h0 + 3] + sBi[h0 + 3];
        *reinterpret_cast<f32x4*>(out + base) = o;
    }
}

extern "C" void kernel_launch(void* const* d_in, const int* in_sizes, int n_in,
                              void* d_out, int out_size, void* d_ws, size_t ws_size,
                              hipStream_t stream) {
    const float* x  = (const float*)d_in[0];
    const float* sb = (const float*)d_in[1];
    const float* w  = (const float*)d_in[2];
    const float* bi = (const float*)d_in[3];
    float* out = (float*)d_out;

    // workspace: partials [nsplit][B][3*H] fp32
    int nsplit = 16;
    while (nsplit > 1 &&
           ((size_t)nsplit * B_DIM * 3 * H_DIM * sizeof(float)) > ws_size)
        nsplit >>= 1;
    float* partials = (float*)d_ws;

    k_partial<<<dim3(B_DIM, nsplit), 256, 0, stream>>>(x, partials, S_LEN / nsplit);
    k_final<<<B_DIM * (S_LEN / FB_ROWS), 256, 0, stream>>>(x, partials, sb, w, bi, out,
                                                           nsplit);
}